// Round 23
// baseline (234.981 us; speedup 1.0000x reference)
//
#include <hip/hip_runtime.h>

// DyHuCoG: out = (E + A*E + A*(A*E)) / 3
// E: [N,32] f32, A: COO (vals f32, row i32, col i32), N=100001, nE=6400000.
//
// Pipeline (atomic-free (row,colhalf)-partition, 4B edges, col-split SpMM):
//   1) tile_hist: per-4096-edge tile histogram over 782 partitions
//   2) colscan:   out-of-place column scan -> colbase + partition totals
//   3) scan_buckets: partition bases
//   4) partition_edges3: LDS payload staging (39KB, ~4 blk/CU), no hist
//      pass (runoff from tileCnt row), coalesced run writes
//   5) csr_sort6: one block per partition, reads only its own range (2x),
//      256-key (rowlow) LDS-staged sort -> cv2 (4B/edge) + seg[] bases
//   6) cast emb -> bf16 pairs
//   7) layer1 in 2 col phases (3.2MB gather set, L2-resident), 4 lanes/row,
//      uint4 gathers (one 64B line/edge): phase0 -> f32 partials, ph1 -> yd
//   8) layer2 same, phase1 fused with final combine

constexpr int D = 32;
constexpr int RPB_LOG = 8;               // rows per bucket = 256
constexpr int RPB = 1 << RPB_LOG;
constexpr int MAXNB = 800;               // max partitions (n <= 102400)
constexpr int TILE = 4096;               // edges per partition tile
constexpr int PT2 = 512;                 // partition threads
constexpr int CAP = 9728;                // LDS staging capacity (edges/part)
constexpr float QSCALE = 32768.0f;       // 15-bit val quantization
constexpr float QINV = 1.0f / 32768.0f;

__device__ __forceinline__ unsigned short f2bf(float f) {
    unsigned u = __float_as_uint(f);
    unsigned r = (u + 0x7FFFu + ((u >> 16) & 1u)) >> 16;   // RNE
    return (unsigned short)r;
}
__device__ __forceinline__ float lo_f(unsigned v) {       // bf16 pair low
    return __uint_as_float(v << 16);
}
__device__ __forceinline__ float hi_f(unsigned v) {       // bf16 pair high
    return __uint_as_float(v & 0xFFFF0000u);
}

__global__ void zero_f32(float* __restrict__ p, int n) {
    int i = blockIdx.x * blockDim.x + threadIdx.x;
    if (i < n) p[i] = 0.0f;
}
__global__ void cast_bf16(const float* __restrict__ in,
                          unsigned short* __restrict__ out, int n) {
    int i = blockIdx.x * blockDim.x + threadIdx.x;
    if (i < n) out[i] = f2bf(in[i]);
}

// ------- 1) per-tile partition histogram -> tileCnt[tile][NBp] -----------
__global__ __launch_bounds__(256) void tile_hist(
    const int* __restrict__ row, const int* __restrict__ col,
    int* __restrict__ tileCnt, int nE, int NBp, int half) {
    __shared__ int h[MAXNB];
    int tile = blockIdx.x;
    int base = tile * TILE;
    int n = min(TILE, nE - base);
    int t = threadIdx.x;
    for (int i = t; i < NBp; i += 256) h[i] = 0;
    __syncthreads();
    for (int i = t; i < n; i += 256) {
        int b = ((row[base + i] >> RPB_LOG) << 1) |
                ((col[base + i] >= half) ? 1 : 0);
        atomicAdd(&h[b], 1);
    }
    __syncthreads();
    for (int i = t; i < NBp; i += 256)
        tileCnt[(size_t)tile * NBp + i] = h[i];
}

// ------- 2) out-of-place column scan: tileCnt -> colbase + totals --------
__global__ __launch_bounds__(256) void colscan(
    const int* __restrict__ tileCnt, int* __restrict__ colbase,
    int* __restrict__ cnt, int nTiles, int NBp) {
    __shared__ int s2[256];
    __shared__ int carryS;
    int b = blockIdx.x, t = threadIdx.x;
    if (t == 0) carryS = 0;
    __syncthreads();
    for (int c0 = 0; c0 < nTiles; c0 += 1024) {
        int v[4], idx[4];
        int sum = 0;
#pragma unroll
        for (int k = 0; k < 4; ++k) {
            idx[k] = c0 + t * 4 + k;
            v[k] = (idx[k] < nTiles) ? tileCnt[(size_t)idx[k] * NBp + b] : 0;
            sum += v[k];
        }
        s2[t] = sum;
        __syncthreads();
        for (int o = 1; o < 256; o <<= 1) {
            int x = (t >= o) ? s2[t - o] : 0;
            __syncthreads();
            s2[t] += x;
            __syncthreads();
        }
        int run = ((t == 0) ? 0 : s2[t - 1]) + carryS;
#pragma unroll
        for (int k = 0; k < 4; ++k) {
            if (idx[k] < nTiles) colbase[(size_t)idx[k] * NBp + b] = run;
            run += v[k];
        }
        __syncthreads();
        if (t == 0) carryS += s2[255];
        __syncthreads();
    }
    if (t == 0) cnt[b] = carryS;
}

// ---------------- 3) exclusive scan of partition counts (<= 1024) --------
__global__ __launch_bounds__(1024) void scan_buckets(
    const int* __restrict__ cnt, int* __restrict__ bases, int NBp, int nE) {
    __shared__ int s[1024];
    int t = threadIdx.x;
    s[t] = (t < NBp) ? cnt[t] : 0;
    __syncthreads();
    for (int o = 1; o < 1024; o <<= 1) {
        int v = (t >= o) ? s[t - o] : 0;
        __syncthreads();
        s[t] += v;
        __syncthreads();
    }
    if (t < NBp) bases[t] = (t == 0) ? 0 : s[t - 1];
    if (t == 0) bases[NBp] = nE;
}

// ------- 4) tiled partition, LDS payload staging, coalesced writes -------
__global__ __launch_bounds__(PT2) void partition_edges3(
    const int* __restrict__ row, const int* __restrict__ col,
    const float* __restrict__ vals, const int* __restrict__ bases,
    const int* __restrict__ tileCnt, const int* __restrict__ colbase,
    uint2* __restrict__ cv, int nE, int NBp, int half) {
    __shared__ uint2 buf[TILE];            // 32 KB (also scan scratch)
    __shared__ int hist[MAXNB];            // 3.2 KB (runbase - runoff0)
    __shared__ int runoff[MAXNB];          // 3.2 KB (running local cursor)
    int* s2 = (int*)buf;                   // scratch (buf unused pre-reorder)
    int t = threadIdx.x;
    int tile = blockIdx.x;
    int base = tile * TILE;
    int n = min(TILE, nE - base);
    if (n <= 0) return;
    // local exclusive scan of tileCnt[tile][*] -> runoff (2 elems/thread)
    int b2 = t * 2;
    int a0 = (b2 + 0 < NBp) ? tileCnt[(size_t)tile * NBp + b2 + 0] : 0;
    int a1 = (b2 + 1 < NBp) ? tileCnt[(size_t)tile * NBp + b2 + 1] : 0;
    s2[t] = a0 + a1;
    __syncthreads();
    for (int o = 1; o < PT2; o <<= 1) {
        int v = (t >= o) ? s2[t - o] : 0;
        __syncthreads();
        s2[t] += v;
        __syncthreads();
    }
    {
        int excl = (t == 0) ? 0 : s2[t - 1];
        if (b2 + 0 < NBp) runoff[b2 + 0] = excl;
        if (b2 + 1 < NBp) runoff[b2 + 1] = excl + a0;
    }
    __syncthreads();
    // hist[b] := global run base - runoff0[b]
    for (int i = t; i < NBp; i += PT2)
        hist[i] = bases[i] + colbase[(size_t)tile * NBp + i] - runoff[i];
    __syncthreads();
    // reorder into LDS partition-major; partition id packed in y bits 15..24
    for (int i = t; i < n; i += PT2) {
        int r = row[base + i];
        int c = col[base + i];
        int b = ((r >> RPB_LOG) << 1) | ((c >= half) ? 1 : 0);
        int slot = atomicAdd(&runoff[b], 1);
        float v = vals[base + i];
        int q = __float2int_rn(v * QSCALE);
        q = max(0, min(32767, q));
        uint2 p;
        p.x = (unsigned)c | ((unsigned)(r & (RPB - 1)) << 17);
        p.y = (unsigned)q | ((unsigned)b << 15);
        buf[slot] = p;
    }
    __syncthreads();
    // coalesced run writes: dest = hist[b] + slot (slot == i)
    for (int i = t; i < n; i += PT2) {
        uint2 v = buf[i];
        cv[hist[v.y >> 15] + i] = v;
    }
}

// ---- 5) per-partition 256-key LDS-staged sort -> cv2 + seg --------------
__global__ __launch_bounds__(512) void csr_sort6(
    const int* __restrict__ bases, const uint2* __restrict__ cv,
    unsigned* __restrict__ cv2, int* __restrict__ seg, int nSegTot, int nE) {
    __shared__ unsigned stage[CAP];        // 38 KB
    __shared__ int hist_s[RPB];            // 1 KB
    __shared__ int cur_s[RPB];             // 1 KB
    int t = threadIdx.x;
    int p = blockIdx.x;
    int s = bases[p], e = bases[p + 1];
    if (t < RPB) hist_s[t] = 0;
    __syncthreads();
    // pass 1: rowlow histogram of own range
    for (int i = s + t; i < e; i += 512)
        atomicAdd(&hist_s[cv[i].x >> 17], 1);
    __syncthreads();
    if (t < RPB) cur_s[t] = hist_s[t];
    __syncthreads();
    for (int o = 1; o < RPB; o <<= 1) {       // inclusive scan
        int v = 0;
        if (t < RPB && t >= o) v = cur_s[t - o];
        __syncthreads();
        if (t < RPB) cur_s[t] += v;
        __syncthreads();
    }
    int excl = 0;
    if (t < RPB) excl = (t == 0) ? 0 : cur_s[t - 1];
    __syncthreads();
    if (t < RPB) {
        seg[((size_t)p << 8) | t] = s + excl;
        cur_s[t] = excl;                      // local staging cursor
    }
    if (p == 0 && t == 0) seg[nSegTot] = nE;
    __syncthreads();
    int cnt = e - s;
    bool fits = (cnt <= CAP);
    // pass 2: re-read own range, stage (or direct-scatter on overflow)
    for (int i = s + t; i < e; i += 512) {
        uint2 pr = cv[i];
        int k = (int)(pr.x >> 17);
        int slot = atomicAdd(&cur_s[k], 1);
        unsigned packed = (pr.x & 0x1FFFFu) | ((pr.y & 0x7FFFu) << 17);
        if (fits) stage[slot] = packed;
        else      cv2[s + slot] = packed;
    }
    __syncthreads();
    // pass 3: coalesced write
    if (fits) {
        for (int j = t; j < cnt; j += 512)
            cv2[s + j] = stage[j];
    }
}

// ---- 7) layer-1 SpMM, 2 phases, 4 lanes/row, uint4 (8xbf16) gathers -----
template <int PHASE>
__global__ __launch_bounds__(256) void spmm_l1(
    const int* __restrict__ seg, const unsigned* __restrict__ cv,
    const uint4* __restrict__ xd4, float4* __restrict__ part8,
    uint4* __restrict__ yd4, int nRows) {
    int g = (blockIdx.x * 256 + threadIdx.x) >> 2;
    if (g >= nRows) return;
    int lane = threadIdx.x & 3;
    int si = ((g >> 8) << 9) | (PHASE << 8) | (g & 255);
    int e = seg[si], end = seg[si + 1];
    float a0 = 0.0f, a1 = 0.0f, a2 = 0.0f, a3 = 0.0f;
    float a4 = 0.0f, a5 = 0.0f, a6 = 0.0f, a7 = 0.0f;
    for (; e + 4 <= end; e += 4) {
        unsigned q0 = cv[e], q1 = cv[e + 1], q2 = cv[e + 2], q3 = cv[e + 3];
        uint4 v0 = xd4[(size_t)(q0 & 0x1FFFFu) * 4 + lane];
        uint4 v1 = xd4[(size_t)(q1 & 0x1FFFFu) * 4 + lane];
        uint4 v2 = xd4[(size_t)(q2 & 0x1FFFFu) * 4 + lane];
        uint4 v3 = xd4[(size_t)(q3 & 0x1FFFFu) * 4 + lane];
        float s0 = (float)(q0 >> 17), s1 = (float)(q1 >> 17);
        float s2 = (float)(q2 >> 17), s3 = (float)(q3 >> 17);
        a0 += s0 * lo_f(v0.x);  a1 += s0 * hi_f(v0.x);
        a2 += s0 * lo_f(v0.y);  a3 += s0 * hi_f(v0.y);
        a4 += s0 * lo_f(v0.z);  a5 += s0 * hi_f(v0.z);
        a6 += s0 * lo_f(v0.w);  a7 += s0 * hi_f(v0.w);
        a0 += s1 * lo_f(v1.x);  a1 += s1 * hi_f(v1.x);
        a2 += s1 * lo_f(v1.y);  a3 += s1 * hi_f(v1.y);
        a4 += s1 * lo_f(v1.z);  a5 += s1 * hi_f(v1.z);
        a6 += s1 * lo_f(v1.w);  a7 += s1 * hi_f(v1.w);
        a0 += s2 * lo_f(v2.x);  a1 += s2 * hi_f(v2.x);
        a2 += s2 * lo_f(v2.y);  a3 += s2 * hi_f(v2.y);
        a4 += s2 * lo_f(v2.z);  a5 += s2 * hi_f(v2.z);
        a6 += s2 * lo_f(v2.w);  a7 += s2 * hi_f(v2.w);
        a0 += s3 * lo_f(v3.x);  a1 += s3 * hi_f(v3.x);
        a2 += s3 * lo_f(v3.y);  a3 += s3 * hi_f(v3.y);
        a4 += s3 * lo_f(v3.z);  a5 += s3 * hi_f(v3.z);
        a6 += s3 * lo_f(v3.w);  a7 += s3 * hi_f(v3.w);
    }
    for (; e < end; ++e) {
        unsigned q = cv[e];
        uint4 v = xd4[(size_t)(q & 0x1FFFFu) * 4 + lane];
        float s = (float)(q >> 17);
        a0 += s * lo_f(v.x);  a1 += s * hi_f(v.x);
        a2 += s * lo_f(v.y);  a3 += s * hi_f(v.y);
        a4 += s * lo_f(v.z);  a5 += s * hi_f(v.z);
        a6 += s * lo_f(v.w);  a7 += s * hi_f(v.w);
    }
    size_t idx = (size_t)g * 4 + lane;
    if (PHASE == 0) {
        part8[idx * 2 + 0] = make_float4(a0, a1, a2, a3);
        part8[idx * 2 + 1] = make_float4(a4, a5, a6, a7);
    } else {
        float4 p0 = part8[idx * 2 + 0];
        float4 p1 = part8[idx * 2 + 1];
        uint4 o;
        o.x = (unsigned)f2bf((p0.x + a0) * QINV) |
              ((unsigned)f2bf((p0.y + a1) * QINV) << 16);
        o.y = (unsigned)f2bf((p0.z + a2) * QINV) |
              ((unsigned)f2bf((p0.w + a3) * QINV) << 16);
        o.z = (unsigned)f2bf((p1.x + a4) * QINV) |
              ((unsigned)f2bf((p1.y + a5) * QINV) << 16);
        o.w = (unsigned)f2bf((p1.z + a6) * QINV) |
              ((unsigned)f2bf((p1.w + a7) * QINV) << 16);
        yd4[idx] = o;
    }
}

// ---- 8) layer-2 SpMM, 2 phases, phase 1 fused with combine --------------
template <int PHASE>
__global__ __launch_bounds__(256) void spmm_l2(
    const int* __restrict__ seg, const unsigned* __restrict__ cv,
    const uint4* __restrict__ yd4, const float4* __restrict__ emb4,
    float4* __restrict__ part8, float4* __restrict__ out4, int nRows) {
    int g = (blockIdx.x * 256 + threadIdx.x) >> 2;
    if (g >= nRows) return;
    int lane = threadIdx.x & 3;
    int si = ((g >> 8) << 9) | (PHASE << 8) | (g & 255);
    int e = seg[si], end = seg[si + 1];
    float a0 = 0.0f, a1 = 0.0f, a2 = 0.0f, a3 = 0.0f;
    float a4 = 0.0f, a5 = 0.0f, a6 = 0.0f, a7 = 0.0f;
    for (; e + 4 <= end; e += 4) {
        unsigned q0 = cv[e], q1 = cv[e + 1], q2 = cv[e + 2], q3 = cv[e + 3];
        uint4 v0 = yd4[(size_t)(q0 & 0x1FFFFu) * 4 + lane];
        uint4 v1 = yd4[(size_t)(q1 & 0x1FFFFu) * 4 + lane];
        uint4 v2 = yd4[(size_t)(q2 & 0x1FFFFu) * 4 + lane];
        uint4 v3 = yd4[(size_t)(q3 & 0x1FFFFu) * 4 + lane];
        float s0 = (float)(q0 >> 17), s1 = (float)(q1 >> 17);
        float s2 = (float)(q2 >> 17), s3 = (float)(q3 >> 17);
        a0 += s0 * lo_f(v0.x);  a1 += s0 * hi_f(v0.x);
        a2 += s0 * lo_f(v0.y);  a3 += s0 * hi_f(v0.y);
        a4 += s0 * lo_f(v0.z);  a5 += s0 * hi_f(v0.z);
        a6 += s0 * lo_f(v0.w);  a7 += s0 * hi_f(v0.w);
        a0 += s1 * lo_f(v1.x);  a1 += s1 * hi_f(v1.x);
        a2 += s1 * lo_f(v1.y);  a3 += s1 * hi_f(v1.y);
        a4 += s1 * lo_f(v1.z);  a5 += s1 * hi_f(v1.z);
        a6 += s1 * lo_f(v1.w);  a7 += s1 * hi_f(v1.w);
        a0 += s2 * lo_f(v2.x);  a1 += s2 * hi_f(v2.x);
        a2 += s2 * lo_f(v2.y);  a3 += s2 * hi_f(v2.y);
        a4 += s2 * lo_f(v2.z);  a5 += s2 * hi_f(v2.z);
        a6 += s2 * lo_f(v2.w);  a7 += s2 * hi_f(v2.w);
        a0 += s3 * lo_f(v3.x);  a1 += s3 * hi_f(v3.x);
        a2 += s3 * lo_f(v3.y);  a3 += s3 * hi_f(v3.y);
        a4 += s3 * lo_f(v3.z);  a5 += s3 * hi_f(v3.z);
        a6 += s3 * lo_f(v3.w);  a7 += s3 * hi_f(v3.w);
    }
    for (; e < end; ++e) {
        unsigned q = cv[e];
        uint4 v = yd4[(size_t)(q & 0x1FFFFu) * 4 + lane];
        float s = (float)(q >> 17);
        a0 += s * lo_f(v.x);  a1 += s * hi_f(v.x);
        a2 += s * lo_f(v.y);  a3 += s * hi_f(v.y);
        a4 += s * lo_f(v.z);  a5 += s * hi_f(v.z);
        a6 += s * lo_f(v.w);  a7 += s * hi_f(v.w);
    }
    size_t idx = (size_t)g * 4 + lane;
    if (PHASE == 0) {
        part8[idx * 2 + 0] = make_float4(a0, a1, a2, a3);
        part8[idx * 2 + 1] = make_float4(a4, a5, a6, a7);
    } else {
        float4 eb0 = emb4[idx * 2 + 0];
        float4 eb1 = emb4[idx * 2 + 1];
        uint4 yv = yd4[idx];
        float4 p0 = part8[idx * 2 + 0];
        float4 p1 = part8[idx * 2 + 1];
        float4 r0, r1;
        r0.x = (eb0.x + lo_f(yv.x) + (p0.x + a0) * QINV) * (1.0f / 3.0f);
        r0.y = (eb0.y + hi_f(yv.x) + (p0.y + a1) * QINV) * (1.0f / 3.0f);
        r0.z = (eb0.z + lo_f(yv.y) + (p0.z + a2) * QINV) * (1.0f / 3.0f);
        r0.w = (eb0.w + hi_f(yv.y) + (p0.w + a3) * QINV) * (1.0f / 3.0f);
        r1.x = (eb1.x + lo_f(yv.z) + (p1.x + a4) * QINV) * (1.0f / 3.0f);
        r1.y = (eb1.y + hi_f(yv.z) + (p1.y + a5) * QINV) * (1.0f / 3.0f);
        r1.z = (eb1.z + lo_f(yv.w) + (p1.z + a6) * QINV) * (1.0f / 3.0f);
        r1.w = (eb1.w + hi_f(yv.w) + (p1.w + a7) * QINV) * (1.0f / 3.0f);
        out4[idx * 2 + 0] = r0;
        out4[idx * 2 + 1] = r1;
    }
}

// =================== atomic fallback ===================
__global__ __launch_bounds__(256) void spmm_atomic(
    const int* __restrict__ row, const int* __restrict__ col,
    const float* __restrict__ vals, const float* __restrict__ x,
    float* __restrict__ y, int nEdges, float scale) {
    long long t = (long long)blockIdx.x * blockDim.x + threadIdx.x;
    int e = (int)(t >> 5);
    if (e >= nEdges) return;
    int d = (int)(t & 31);
    float g = vals[e] * scale * x[(long long)col[e] * D + d];
    atomicAdd(&y[(long long)row[e] * D + d], g);
}
__global__ void combine_third(const float* __restrict__ emb,
                              const float* __restrict__ y1,
                              float* __restrict__ out, int n) {
    int i = blockIdx.x * blockDim.x + threadIdx.x;
    if (i < n) out[i] = (emb[i] + y1[i]) * (1.0f / 3.0f);
}

extern "C" void kernel_launch(void* const* d_in, const int* in_sizes, int n_in,
                              void* d_out, int out_size, void* d_ws, size_t ws_size,
                              hipStream_t stream) {
    const float* emb  = (const float*)d_in[0];
    const float* vals = (const float*)d_in[1];
    const int*   row  = (const int*)d_in[2];
    const int*   col  = (const int*)d_in[3];
    float* out = (float*)d_out;

    const int nElem  = in_sizes[0];          // N * 32
    const int nEdges = in_sizes[1];
    const int n      = nElem / D;            // 100001
    const int NBb    = (n + RPB - 1) >> RPB_LOG;   // 256-row buckets (391)
    const int NBp    = NBb * 2;                    // partitions (782)
    const int BLK = 256;
    const int nTiles = (nEdges + TILE - 1) / TILE; // 1563
    const int half   = n / 2;
    const int nSegTot = NBp * 256;                 // = NBb*512

    // workspace layout:
    //   cnt(NBp) | bases(NBp+1) | seg(nSegTot+1) | cv(8B*nE) | cv2(4B*nE)
    //   tileCnt + colbase alias cv2 (dead before csr_sort6 writes cv2)
    //   yd4 | xd4 | part8 alias cv (dead after csr_sort6)
    size_t off_cnt   = 0;                                     // NBp ints
    size_t off_bases = off_cnt + (size_t)NBp * 4;             // NBp+1 ints
    size_t off_seg   = off_bases + (size_t)(NBp + 1) * 4;     // nSegTot+1
    size_t off_cv    = (off_seg + (size_t)(nSegTot + 1) * 4 + 63) & ~(size_t)63;
    size_t off_cv2   = off_cv + (size_t)nEdges * 8;
    size_t need      = off_cv2 + (size_t)nEdges * 4;

    size_t sz_tc = (size_t)nTiles * NBp * 4;
    bool aliasFit   = ((size_t)nElem * 8 <= (size_t)nEdges * 8);
    bool tileCntFit = (2 * sz_tc <= (size_t)nEdges * 4);
    bool ok = (NBp <= MAXNB) && (n <= 102400) && (ws_size >= need) &&
              aliasFit && tileCntFit;

    if (!ok) {
        // fallback: atomic-scatter path (needs nElem floats)
        if (ws_size < (size_t)nElem * 4) return;
        float* y1 = (float*)d_ws;
        zero_f32<<<(nElem + BLK - 1) / BLK, BLK, 0, stream>>>(y1, nElem);
        long long threads = (long long)nEdges * 32;
        int blocks = (int)((threads + BLK - 1) / BLK);
        spmm_atomic<<<blocks, BLK, 0, stream>>>(row, col, vals, emb, y1, nEdges, 1.0f);
        combine_third<<<(nElem + BLK - 1) / BLK, BLK, 0, stream>>>(emb, y1, out, nElem);
        spmm_atomic<<<blocks, BLK, 0, stream>>>(row, col, vals, y1, out, nEdges, 1.0f / 3.0f);
        return;
    }

    char* ws = (char*)d_ws;
    int*            cnt     = (int*)(ws + off_cnt);
    int*            bases   = (int*)(ws + off_bases);
    int*            seg     = (int*)(ws + off_seg);
    uint2*          cv      = (uint2*)(ws + off_cv);
    unsigned*       cv2     = (unsigned*)(ws + off_cv2);
    int*            tileCnt = (int*)(ws + off_cv2);           // alias
    int*            colbase = (int*)(ws + off_cv2 + sz_tc);   // alias
    uint4*          yd4     = (uint4*)(ws + off_cv);          // alias (cv dead)
    unsigned short* embh    = (unsigned short*)(ws + off_cv + (size_t)nElem * 2);
    uint4*          xd4     = (uint4*)embh;
    float4*         part8   = (float4*)(ws + off_cv + (size_t)nElem * 4);

    // 1) per-tile partition histograms (counts, kept)
    tile_hist<<<nTiles, 256, 0, stream>>>(row, col, tileCnt, nEdges, NBp, half);

    // 2) out-of-place column scan -> colbase + partition totals
    colscan<<<NBp, 256, 0, stream>>>(tileCnt, colbase, cnt, nTiles, NBp);

    // 3) partition bases
    scan_buckets<<<1, 1024, 0, stream>>>(cnt, bases, NBp, nEdges);

    // 4) atomic-free partition (LDS payload staging)
    partition_edges3<<<nTiles, PT2, 0, stream>>>(row, col, vals, bases,
                                                 tileCnt, colbase, cv,
                                                 nEdges, NBp, half);

    // 5) per-partition 256-key LDS-staged sort -> cv2 + seg
    csr_sort6<<<NBp, 512, 0, stream>>>(bases, cv, cv2, seg, nSegTot, nEdges);

    // 6) embh = bf16(emb)   (cv region is dead now)
    cast_bf16<<<(nElem + BLK - 1) / BLK, BLK, 0, stream>>>(emb, embh, nElem);

    // 7) layer 1: y1 = A*E, two L2-resident phases (4 lanes/row)
    int rowBlocks = (n * 4 + BLK - 1) / BLK;
    spmm_l1<0><<<rowBlocks, BLK, 0, stream>>>(seg, cv2, xd4, part8, yd4, n);
    spmm_l1<1><<<rowBlocks, BLK, 0, stream>>>(seg, cv2, xd4, part8, yd4, n);

    // 8) layer 2 + combine: out = (E + y1 + A*y1)/3
    spmm_l2<0><<<rowBlocks, BLK, 0, stream>>>(seg, cv2, yd4,
                                              (const float4*)emb, part8,
                                              (float4*)out, n);
    spmm_l2<1><<<rowBlocks, BLK, 0, stream>>>(seg, cv2, yd4,
                                              (const float4*)emb, part8,
                                              (float4*)out, n);
}

// Round 24
// 223.985 us; speedup vs baseline: 1.0491x; 1.0491x over previous
//
#include <hip/hip_runtime.h>

// DyHuCoG: out = (E + A*E + A*(A*E)) / 3
// E: [N,32] f32, A: COO (vals f32, row i32, col i32), N=100001, nE=6400000.
//
// FINAL (best measured, round 20 = 223 us):
//   1) tile_hist: per-8192-edge tile histogram over 782 partitions
//      (partition = 256-row bucket x colhalf)
//   2) colscan:   out-of-place column scan -> colbase + partition totals
//   3) scan_buckets: partition bases
//   4) partition_edges3: no hist pass (runoff from tileCnt row), LDS
//      payload staging, coalesced run writes
//   5) csr_sort6: one block per partition, reads only its own range (2x),
//      256-key (rowlow) LDS-staged sort -> cv2 (4B/edge) + seg[] bases
//   6) cast emb -> bf16 pairs
//   7) layer1 in 2 col phases (3.2MB gather set, L2-resident), 8 lanes/row,
//      uint2 gathers, unroll 8: phase0 -> f32x4 partial, phase1 -> yd
//   8) layer2 same, phase1 fused with final combine (float4 I/O)

constexpr int D = 32;
constexpr int RPB_LOG = 8;               // rows per bucket = 256
constexpr int RPB = 1 << RPB_LOG;
constexpr int MAXNB = 800;               // max partitions (n <= 102400)
constexpr int TILE = 8192;               // edges per partition tile
constexpr int PT2 = 512;                 // partition threads
constexpr int CAP = 9728;                // LDS staging capacity (edges/part)
constexpr float QSCALE = 32768.0f;       // 15-bit val quantization
constexpr float QINV = 1.0f / 32768.0f;

__device__ __forceinline__ unsigned short f2bf(float f) {
    unsigned u = __float_as_uint(f);
    unsigned r = (u + 0x7FFFu + ((u >> 16) & 1u)) >> 16;   // RNE
    return (unsigned short)r;
}
__device__ __forceinline__ float lo_f(unsigned v) {       // bf16 pair low
    return __uint_as_float(v << 16);
}
__device__ __forceinline__ float hi_f(unsigned v) {       // bf16 pair high
    return __uint_as_float(v & 0xFFFF0000u);
}

__global__ void zero_f32(float* __restrict__ p, int n) {
    int i = blockIdx.x * blockDim.x + threadIdx.x;
    if (i < n) p[i] = 0.0f;
}
__global__ void cast_bf16(const float* __restrict__ in,
                          unsigned short* __restrict__ out, int n) {
    int i = blockIdx.x * blockDim.x + threadIdx.x;
    if (i < n) out[i] = f2bf(in[i]);
}

// ------- 1) per-tile partition histogram -> tileCnt[tile][NBp] -----------
__global__ __launch_bounds__(256) void tile_hist(
    const int* __restrict__ row, const int* __restrict__ col,
    int* __restrict__ tileCnt, int nE, int NBp, int half) {
    __shared__ int h[MAXNB];
    int tile = blockIdx.x;
    int base = tile * TILE;
    int n = min(TILE, nE - base);
    int t = threadIdx.x;
    for (int i = t; i < NBp; i += 256) h[i] = 0;
    __syncthreads();
    for (int i = t; i < n; i += 256) {
        int b = ((row[base + i] >> RPB_LOG) << 1) |
                ((col[base + i] >= half) ? 1 : 0);
        atomicAdd(&h[b], 1);
    }
    __syncthreads();
    for (int i = t; i < NBp; i += 256)
        tileCnt[(size_t)tile * NBp + i] = h[i];
}

// ------- 2) out-of-place column scan: tileCnt -> colbase + totals --------
__global__ __launch_bounds__(256) void colscan(
    const int* __restrict__ tileCnt, int* __restrict__ colbase,
    int* __restrict__ cnt, int nTiles, int NBp) {
    __shared__ int s2[256];
    __shared__ int carryS;
    int b = blockIdx.x, t = threadIdx.x;
    if (t == 0) carryS = 0;
    __syncthreads();
    for (int c0 = 0; c0 < nTiles; c0 += 1024) {
        int v[4], idx[4];
        int sum = 0;
#pragma unroll
        for (int k = 0; k < 4; ++k) {
            idx[k] = c0 + t * 4 + k;
            v[k] = (idx[k] < nTiles) ? tileCnt[(size_t)idx[k] * NBp + b] : 0;
            sum += v[k];
        }
        s2[t] = sum;
        __syncthreads();
        for (int o = 1; o < 256; o <<= 1) {
            int x = (t >= o) ? s2[t - o] : 0;
            __syncthreads();
            s2[t] += x;
            __syncthreads();
        }
        int run = ((t == 0) ? 0 : s2[t - 1]) + carryS;
#pragma unroll
        for (int k = 0; k < 4; ++k) {
            if (idx[k] < nTiles) colbase[(size_t)idx[k] * NBp + b] = run;
            run += v[k];
        }
        __syncthreads();
        if (t == 0) carryS += s2[255];
        __syncthreads();
    }
    if (t == 0) cnt[b] = carryS;
}

// ---------------- 3) exclusive scan of partition counts (<= 1024) --------
__global__ __launch_bounds__(1024) void scan_buckets(
    const int* __restrict__ cnt, int* __restrict__ bases, int NBp, int nE) {
    __shared__ int s[1024];
    int t = threadIdx.x;
    s[t] = (t < NBp) ? cnt[t] : 0;
    __syncthreads();
    for (int o = 1; o < 1024; o <<= 1) {
        int v = (t >= o) ? s[t - o] : 0;
        __syncthreads();
        s[t] += v;
        __syncthreads();
    }
    if (t < NBp) bases[t] = (t == 0) ? 0 : s[t - 1];
    if (t == 0) bases[NBp] = nE;
}

// ------- 4) tiled partition, NO hist pass, coalesced writes --------------
__global__ __launch_bounds__(PT2) void partition_edges3(
    const int* __restrict__ row, const int* __restrict__ col,
    const float* __restrict__ vals, const int* __restrict__ bases,
    const int* __restrict__ tileCnt, const int* __restrict__ colbase,
    uint2* __restrict__ cv, int nE, int NBp, int half) {
    __shared__ uint2 buf[TILE];            // 64 KB (also scan scratch)
    __shared__ int hist[MAXNB];            // 3.2 KB (runbase - runoff0)
    __shared__ int runoff[MAXNB];          // 3.2 KB (running local cursor)
    int* s2 = (int*)buf;                   // scratch (buf unused pre-reorder)
    int t = threadIdx.x;
    int tile = blockIdx.x;
    int base = tile * TILE;
    int n = min(TILE, nE - base);
    if (n <= 0) return;
    // local exclusive scan of tileCnt[tile][*] -> runoff (2 elems/thread)
    int b2 = t * 2;
    int a0 = (b2 + 0 < NBp) ? tileCnt[(size_t)tile * NBp + b2 + 0] : 0;
    int a1 = (b2 + 1 < NBp) ? tileCnt[(size_t)tile * NBp + b2 + 1] : 0;
    s2[t] = a0 + a1;
    __syncthreads();
    for (int o = 1; o < PT2; o <<= 1) {
        int v = (t >= o) ? s2[t - o] : 0;
        __syncthreads();
        s2[t] += v;
        __syncthreads();
    }
    {
        int excl = (t == 0) ? 0 : s2[t - 1];
        if (b2 + 0 < NBp) runoff[b2 + 0] = excl;
        if (b2 + 1 < NBp) runoff[b2 + 1] = excl + a0;
    }
    __syncthreads();
    // hist[b] := global run base - runoff0[b]
    for (int i = t; i < NBp; i += PT2)
        hist[i] = bases[i] + colbase[(size_t)tile * NBp + i] - runoff[i];
    __syncthreads();
    // reorder into LDS partition-major; partition id packed in y bits 15..24
    for (int i = t; i < n; i += PT2) {
        int r = row[base + i];
        int c = col[base + i];
        int b = ((r >> RPB_LOG) << 1) | ((c >= half) ? 1 : 0);
        int slot = atomicAdd(&runoff[b], 1);
        float v = vals[base + i];
        int q = __float2int_rn(v * QSCALE);
        q = max(0, min(32767, q));
        uint2 p;
        p.x = (unsigned)c | ((unsigned)(r & (RPB - 1)) << 17);
        p.y = (unsigned)q | ((unsigned)b << 15);
        buf[slot] = p;
    }
    __syncthreads();
    // coalesced run writes: dest = hist[b] + slot (slot == i)
    for (int i = t; i < n; i += PT2) {
        uint2 v = buf[i];
        cv[hist[v.y >> 15] + i] = v;
    }
}

// ---- 5) per-partition 256-key LDS-staged sort -> cv2 + seg --------------
__global__ __launch_bounds__(512) void csr_sort6(
    const int* __restrict__ bases, const uint2* __restrict__ cv,
    unsigned* __restrict__ cv2, int* __restrict__ seg, int nSegTot, int nE) {
    __shared__ unsigned stage[CAP];        // 38 KB
    __shared__ int hist_s[RPB];            // 1 KB
    __shared__ int cur_s[RPB];             // 1 KB
    int t = threadIdx.x;
    int p = blockIdx.x;
    int s = bases[p], e = bases[p + 1];
    if (t < RPB) hist_s[t] = 0;
    __syncthreads();
    // pass 1: rowlow histogram of own range
    for (int i = s + t; i < e; i += 512)
        atomicAdd(&hist_s[cv[i].x >> 17], 1);
    __syncthreads();
    if (t < RPB) cur_s[t] = hist_s[t];
    __syncthreads();
    for (int o = 1; o < RPB; o <<= 1) {       // inclusive scan
        int v = 0;
        if (t < RPB && t >= o) v = cur_s[t - o];
        __syncthreads();
        if (t < RPB) cur_s[t] += v;
        __syncthreads();
    }
    int excl = 0;
    if (t < RPB) excl = (t == 0) ? 0 : cur_s[t - 1];
    __syncthreads();
    if (t < RPB) {
        seg[((size_t)p << 8) | t] = s + excl;
        cur_s[t] = excl;                      // local staging cursor
    }
    if (p == 0 && t == 0) seg[nSegTot] = nE;
    __syncthreads();
    int cnt = e - s;
    bool fits = (cnt <= CAP);
    // pass 2: re-read own range, stage (or direct-scatter on overflow)
    for (int i = s + t; i < e; i += 512) {
        uint2 pr = cv[i];
        int k = (int)(pr.x >> 17);
        int slot = atomicAdd(&cur_s[k], 1);
        unsigned packed = (pr.x & 0x1FFFFu) | ((pr.y & 0x7FFFu) << 17);
        if (fits) stage[slot] = packed;
        else      cv2[s + slot] = packed;
    }
    __syncthreads();
    // pass 3: coalesced write
    if (fits) {
        for (int j = t; j < cnt; j += 512)
            cv2[s + j] = stage[j];
    }
}

// ---- 7) layer-1 SpMM, 2 phases, 8 lanes/row, uint2 gathers, unroll 8 ----
template <int PHASE>
__global__ __launch_bounds__(256) void spmm_l1(
    const int* __restrict__ seg, const unsigned* __restrict__ cv,
    const uint2* __restrict__ xd2, float4* __restrict__ part4,
    uint2* __restrict__ yd2, int nRows) {
    int g = (blockIdx.x * 256 + threadIdx.x) >> 3;
    if (g >= nRows) return;
    int lane = threadIdx.x & 7;
    int si = ((g >> 8) << 9) | (PHASE << 8) | (g & 255);
    int e = seg[si], end = seg[si + 1];
    float a0 = 0.0f, a1 = 0.0f, a2 = 0.0f, a3 = 0.0f;
    for (; e + 8 <= end; e += 8) {
        unsigned q0 = cv[e], q1 = cv[e + 1], q2 = cv[e + 2], q3 = cv[e + 3];
        unsigned q4 = cv[e + 4], q5 = cv[e + 5], q6 = cv[e + 6], q7 = cv[e + 7];
        uint2 v0 = xd2[(size_t)(q0 & 0x1FFFFu) * 8 + lane];
        uint2 v1 = xd2[(size_t)(q1 & 0x1FFFFu) * 8 + lane];
        uint2 v2 = xd2[(size_t)(q2 & 0x1FFFFu) * 8 + lane];
        uint2 v3 = xd2[(size_t)(q3 & 0x1FFFFu) * 8 + lane];
        uint2 v4 = xd2[(size_t)(q4 & 0x1FFFFu) * 8 + lane];
        uint2 v5 = xd2[(size_t)(q5 & 0x1FFFFu) * 8 + lane];
        uint2 v6 = xd2[(size_t)(q6 & 0x1FFFFu) * 8 + lane];
        uint2 v7 = xd2[(size_t)(q7 & 0x1FFFFu) * 8 + lane];
        float s0 = (float)(q0 >> 17), s1 = (float)(q1 >> 17);
        float s2 = (float)(q2 >> 17), s3 = (float)(q3 >> 17);
        float s4 = (float)(q4 >> 17), s5 = (float)(q5 >> 17);
        float s6 = (float)(q6 >> 17), s7 = (float)(q7 >> 17);
        a0 += s0 * lo_f(v0.x);  a1 += s0 * hi_f(v0.x);
        a2 += s0 * lo_f(v0.y);  a3 += s0 * hi_f(v0.y);
        a0 += s1 * lo_f(v1.x);  a1 += s1 * hi_f(v1.x);
        a2 += s1 * lo_f(v1.y);  a3 += s1 * hi_f(v1.y);
        a0 += s2 * lo_f(v2.x);  a1 += s2 * hi_f(v2.x);
        a2 += s2 * lo_f(v2.y);  a3 += s2 * hi_f(v2.y);
        a0 += s3 * lo_f(v3.x);  a1 += s3 * hi_f(v3.x);
        a2 += s3 * lo_f(v3.y);  a3 += s3 * hi_f(v3.y);
        a0 += s4 * lo_f(v4.x);  a1 += s4 * hi_f(v4.x);
        a2 += s4 * lo_f(v4.y);  a3 += s4 * hi_f(v4.y);
        a0 += s5 * lo_f(v5.x);  a1 += s5 * hi_f(v5.x);
        a2 += s5 * lo_f(v5.y);  a3 += s5 * hi_f(v5.y);
        a0 += s6 * lo_f(v6.x);  a1 += s6 * hi_f(v6.x);
        a2 += s6 * lo_f(v6.y);  a3 += s6 * hi_f(v6.y);
        a0 += s7 * lo_f(v7.x);  a1 += s7 * hi_f(v7.x);
        a2 += s7 * lo_f(v7.y);  a3 += s7 * hi_f(v7.y);
    }
    for (; e < end; ++e) {
        unsigned q = cv[e];
        uint2 v = xd2[(size_t)(q & 0x1FFFFu) * 8 + lane];
        float s = (float)(q >> 17);
        a0 += s * lo_f(v.x);  a1 += s * hi_f(v.x);
        a2 += s * lo_f(v.y);  a3 += s * hi_f(v.y);
    }
    size_t idx = (size_t)g * 8 + lane;
    if (PHASE == 0) {
        part4[idx] = make_float4(a0, a1, a2, a3);
    } else {
        float4 p = part4[idx];
        uint2 o;
        o.x = (unsigned)f2bf((p.x + a0) * QINV) |
              ((unsigned)f2bf((p.y + a1) * QINV) << 16);
        o.y = (unsigned)f2bf((p.z + a2) * QINV) |
              ((unsigned)f2bf((p.w + a3) * QINV) << 16);
        yd2[idx] = o;
    }
}

// ---- 8) layer-2 SpMM, 2 phases, phase 1 fused with combine --------------
template <int PHASE>
__global__ __launch_bounds__(256) void spmm_l2(
    const int* __restrict__ seg, const unsigned* __restrict__ cv,
    const uint2* __restrict__ yd2, const float4* __restrict__ emb4,
    float4* __restrict__ part4, float4* __restrict__ out4, int nRows) {
    int g = (blockIdx.x * 256 + threadIdx.x) >> 3;
    if (g >= nRows) return;
    int lane = threadIdx.x & 7;
    int si = ((g >> 8) << 9) | (PHASE << 8) | (g & 255);
    int e = seg[si], end = seg[si + 1];
    float a0 = 0.0f, a1 = 0.0f, a2 = 0.0f, a3 = 0.0f;
    for (; e + 8 <= end; e += 8) {
        unsigned q0 = cv[e], q1 = cv[e + 1], q2 = cv[e + 2], q3 = cv[e + 3];
        unsigned q4 = cv[e + 4], q5 = cv[e + 5], q6 = cv[e + 6], q7 = cv[e + 7];
        uint2 v0 = yd2[(size_t)(q0 & 0x1FFFFu) * 8 + lane];
        uint2 v1 = yd2[(size_t)(q1 & 0x1FFFFu) * 8 + lane];
        uint2 v2 = yd2[(size_t)(q2 & 0x1FFFFu) * 8 + lane];
        uint2 v3 = yd2[(size_t)(q3 & 0x1FFFFu) * 8 + lane];
        uint2 v4 = yd2[(size_t)(q4 & 0x1FFFFu) * 8 + lane];
        uint2 v5 = yd2[(size_t)(q5 & 0x1FFFFu) * 8 + lane];
        uint2 v6 = yd2[(size_t)(q6 & 0x1FFFFu) * 8 + lane];
        uint2 v7 = yd2[(size_t)(q7 & 0x1FFFFu) * 8 + lane];
        float s0 = (float)(q0 >> 17), s1 = (float)(q1 >> 17);
        float s2 = (float)(q2 >> 17), s3 = (float)(q3 >> 17);
        float s4 = (float)(q4 >> 17), s5 = (float)(q5 >> 17);
        float s6 = (float)(q6 >> 17), s7 = (float)(q7 >> 17);
        a0 += s0 * lo_f(v0.x);  a1 += s0 * hi_f(v0.x);
        a2 += s0 * lo_f(v0.y);  a3 += s0 * hi_f(v0.y);
        a0 += s1 * lo_f(v1.x);  a1 += s1 * hi_f(v1.x);
        a2 += s1 * lo_f(v1.y);  a3 += s1 * hi_f(v1.y);
        a0 += s2 * lo_f(v2.x);  a1 += s2 * hi_f(v2.x);
        a2 += s2 * lo_f(v2.y);  a3 += s2 * hi_f(v2.y);
        a0 += s3 * lo_f(v3.x);  a1 += s3 * hi_f(v3.x);
        a2 += s3 * lo_f(v3.y);  a3 += s3 * hi_f(v3.y);
        a0 += s4 * lo_f(v4.x);  a1 += s4 * hi_f(v4.x);
        a2 += s4 * lo_f(v4.y);  a3 += s4 * hi_f(v4.y);
        a0 += s5 * lo_f(v5.x);  a1 += s5 * hi_f(v5.x);
        a2 += s5 * lo_f(v5.y);  a3 += s5 * hi_f(v5.y);
        a0 += s6 * lo_f(v6.x);  a1 += s6 * hi_f(v6.x);
        a2 += s6 * lo_f(v6.y);  a3 += s6 * hi_f(v6.y);
        a0 += s7 * lo_f(v7.x);  a1 += s7 * hi_f(v7.x);
        a2 += s7 * lo_f(v7.y);  a3 += s7 * hi_f(v7.y);
    }
    for (; e < end; ++e) {
        unsigned q = cv[e];
        uint2 v = yd2[(size_t)(q & 0x1FFFFu) * 8 + lane];
        float s = (float)(q >> 17);
        a0 += s * lo_f(v.x);  a1 += s * hi_f(v.x);
        a2 += s * lo_f(v.y);  a3 += s * hi_f(v.y);
    }
    size_t idx = (size_t)g * 8 + lane;
    if (PHASE == 0) {
        part4[idx] = make_float4(a0, a1, a2, a3);
    } else {
        float4 eb = emb4[idx];
        uint2 yv = yd2[idx];
        float4 p = part4[idx];
        float4 r;
        r.x = (eb.x + lo_f(yv.x) + (p.x + a0) * QINV) * (1.0f / 3.0f);
        r.y = (eb.y + hi_f(yv.x) + (p.y + a1) * QINV) * (1.0f / 3.0f);
        r.z = (eb.z + lo_f(yv.y) + (p.z + a2) * QINV) * (1.0f / 3.0f);
        r.w = (eb.w + hi_f(yv.y) + (p.w + a3) * QINV) * (1.0f / 3.0f);
        out4[idx] = r;
    }
}

// =================== atomic fallback ===================
__global__ __launch_bounds__(256) void spmm_atomic(
    const int* __restrict__ row, const int* __restrict__ col,
    const float* __restrict__ vals, const float* __restrict__ x,
    float* __restrict__ y, int nEdges, float scale) {
    long long t = (long long)blockIdx.x * blockDim.x + threadIdx.x;
    int e = (int)(t >> 5);
    if (e >= nEdges) return;
    int d = (int)(t & 31);
    float g = vals[e] * scale * x[(long long)col[e] * D + d];
    atomicAdd(&y[(long long)row[e] * D + d], g);
}
__global__ void combine_third(const float* __restrict__ emb,
                              const float* __restrict__ y1,
                              float* __restrict__ out, int n) {
    int i = blockIdx.x * blockDim.x + threadIdx.x;
    if (i < n) out[i] = (emb[i] + y1[i]) * (1.0f / 3.0f);
}

extern "C" void kernel_launch(void* const* d_in, const int* in_sizes, int n_in,
                              void* d_out, int out_size, void* d_ws, size_t ws_size,
                              hipStream_t stream) {
    const float* emb  = (const float*)d_in[0];
    const float* vals = (const float*)d_in[1];
    const int*   row  = (const int*)d_in[2];
    const int*   col  = (const int*)d_in[3];
    float* out = (float*)d_out;

    const int nElem  = in_sizes[0];          // N * 32
    const int nEdges = in_sizes[1];
    const int n      = nElem / D;            // 100001
    const int NBb    = (n + RPB - 1) >> RPB_LOG;   // 256-row buckets (391)
    const int NBp    = NBb * 2;                    // partitions (782)
    const int BLK = 256;
    const int nTiles = (nEdges + TILE - 1) / TILE; // 782
    const int half   = n / 2;
    const int nSegTot = NBp * 256;                 // = NBb*512

    // workspace layout:
    //   cnt(NBp) | bases(NBp+1) | seg(nSegTot+1) | cv(8B*nE) | cv2(4B*nE)
    //   tileCnt + colbase alias cv2 (dead before csr_sort6 writes cv2)
    //   yd2 | xd2 | part4 alias cv (dead after csr_sort6)
    size_t off_cnt   = 0;                                     // NBp ints
    size_t off_bases = off_cnt + (size_t)NBp * 4;             // NBp+1 ints
    size_t off_seg   = off_bases + (size_t)(NBp + 1) * 4;     // nSegTot+1
    size_t off_cv    = (off_seg + (size_t)(nSegTot + 1) * 4 + 63) & ~(size_t)63;
    size_t off_cv2   = off_cv + (size_t)nEdges * 8;
    size_t need      = off_cv2 + (size_t)nEdges * 4;

    size_t sz_tc = (size_t)nTiles * NBp * 4;
    bool aliasFit   = ((size_t)nElem * 8 <= (size_t)nEdges * 8);
    bool tileCntFit = (2 * sz_tc <= (size_t)nEdges * 4);
    bool ok = (NBp <= MAXNB) && (n <= 102400) && (ws_size >= need) &&
              aliasFit && tileCntFit;

    if (!ok) {
        // fallback: atomic-scatter path (needs nElem floats)
        if (ws_size < (size_t)nElem * 4) return;
        float* y1 = (float*)d_ws;
        zero_f32<<<(nElem + BLK - 1) / BLK, BLK, 0, stream>>>(y1, nElem);
        long long threads = (long long)nEdges * 32;
        int blocks = (int)((threads + BLK - 1) / BLK);
        spmm_atomic<<<blocks, BLK, 0, stream>>>(row, col, vals, emb, y1, nEdges, 1.0f);
        combine_third<<<(nElem + BLK - 1) / BLK, BLK, 0, stream>>>(emb, y1, out, nElem);
        spmm_atomic<<<blocks, BLK, 0, stream>>>(row, col, vals, y1, out, nEdges, 1.0f / 3.0f);
        return;
    }

    char* ws = (char*)d_ws;
    int*            cnt     = (int*)(ws + off_cnt);
    int*            bases   = (int*)(ws + off_bases);
    int*            seg     = (int*)(ws + off_seg);
    uint2*          cv      = (uint2*)(ws + off_cv);
    unsigned*       cv2     = (unsigned*)(ws + off_cv2);
    int*            tileCnt = (int*)(ws + off_cv2);           // alias
    int*            colbase = (int*)(ws + off_cv2 + sz_tc);   // alias
    uint2*          yd2     = (uint2*)(ws + off_cv);          // alias (cv dead)
    unsigned short* embh    = (unsigned short*)(ws + off_cv + (size_t)nElem * 2);
    uint2*          xd2     = (uint2*)embh;
    float4*         part4   = (float4*)(ws + off_cv + (size_t)nElem * 4);

    // 1) per-tile partition histograms (counts, kept)
    tile_hist<<<nTiles, 256, 0, stream>>>(row, col, tileCnt, nEdges, NBp, half);

    // 2) out-of-place column scan -> colbase + partition totals
    colscan<<<NBp, 256, 0, stream>>>(tileCnt, colbase, cnt, nTiles, NBp);

    // 3) partition bases
    scan_buckets<<<1, 1024, 0, stream>>>(cnt, bases, NBp, nEdges);

    // 4) atomic-free partition (no hist pass; runoff from tileCnt row)
    partition_edges3<<<nTiles, PT2, 0, stream>>>(row, col, vals, bases,
                                                 tileCnt, colbase, cv,
                                                 nEdges, NBp, half);

    // 5) per-partition 256-key LDS-staged sort -> cv2 + seg
    csr_sort6<<<NBp, 512, 0, stream>>>(bases, cv, cv2, seg, nSegTot, nEdges);

    // 6) embh = bf16(emb)   (cv region is dead now)
    cast_bf16<<<(nElem + BLK - 1) / BLK, BLK, 0, stream>>>(emb, embh, nElem);

    // 7) layer 1: y1 = A*E, two L2-resident phases (8 lanes/row)
    int rowBlocks = (n * 8 + BLK - 1) / BLK;
    spmm_l1<0><<<rowBlocks, BLK, 0, stream>>>(seg, cv2, xd2, part4, yd2, n);
    spmm_l1<1><<<rowBlocks, BLK, 0, stream>>>(seg, cv2, xd2, part4, yd2, n);

    // 8) layer 2 + combine: out = (E + y1 + A*y1)/3
    spmm_l2<0><<<rowBlocks, BLK, 0, stream>>>(seg, cv2, yd2,
                                              (const float4*)emb, part4,
                                              (float4*)out, n);
    spmm_l2<1><<<rowBlocks, BLK, 0, stream>>>(seg, cv2, yd2,
                                              (const float4*)emb, part4,
                                              (float4*)out, n);
}